// Round 7
// baseline (152.801 us; speedup 1.0000x reference)
//
#include <hip/hip_runtime.h>
#include <hip/hip_bf16.h>
#include <stdint.h>

// Problem constants
#define B_  8
#define S_  1024
#define H_  1024
#define NH_ 16
#define HD_ 64
#define M_  (B_*S_)   // 8192 rows of hidden

using bf16x8 = __attribute__((ext_vector_type(8))) __bf16;
using f32x4  = __attribute__((ext_vector_type(4))) float;
using f32x16 = __attribute__((ext_vector_type(16))) float;
typedef int iv2 __attribute__((ext_vector_type(2)));

#define LOG2E 1.4426950408889634f

#if __has_builtin(__builtin_amdgcn_exp2f)
#define EXP2(x) __builtin_amdgcn_exp2f(x)
#else
#define EXP2(x) exp2f(x)
#endif

#define SBAR() asm volatile("s_barrier" ::: "memory")
#define WAITV(n) asm volatile("s_waitcnt vmcnt(" #n ")" ::: "memory")

// async global->LDS, 16B per lane; lds ptr must be wave-uniform (HW adds lane*16)
__device__ __forceinline__ void gload_lds16(const void* g, void* l) {
  __builtin_amdgcn_global_load_lds(
      (const __attribute__((address_space(1))) unsigned int*)g,
      (__attribute__((address_space(3))) unsigned int*)l, 16, 0, 0);
}

// pack two f32 -> one u32 of 2 bf16 (lo in bits 0-15)
__device__ __forceinline__ unsigned pack_bf16(float lo, float hi) {
  unsigned r;
  asm("v_cvt_pk_bf16_f32 %0, %1, %2" : "=v"(r) : "v"(lo), "v"(hi));
  return r;
}

// swap a.hi32lanes <-> b.lo32lanes
__device__ __forceinline__ void swapl32(unsigned& a, unsigned& b) {
#if __has_builtin(__builtin_amdgcn_permlane32_swap)
  iv2 r = __builtin_amdgcn_permlane32_swap((int)a, (int)b, false, false);
  a = (unsigned)r[0];
  b = (unsigned)r[1];
#else
  unsigned axc = (unsigned)__shfl_xor((int)a, 32);
  unsigned bxc = (unsigned)__shfl_xor((int)b, 32);
  int lane = threadIdx.x & 63;
  unsigned an = (lane < 32) ? a : bxc;
  unsigned bn = (lane < 32) ? axc : b;
  a = an; b = bn;
#endif
}

// ---------------------------------------------------------------------------
// fp32 -> bf16 casts. X: one launch. W's: one fused launch into contiguous dst.
// ---------------------------------------------------------------------------
__global__ void __launch_bounds__(256) cast_bf16_kernel(const float* __restrict__ in,
                                                        __bf16* __restrict__ out, int n8) {
  int i = blockIdx.x * blockDim.x + threadIdx.x;
  int stride = gridDim.x * blockDim.x;
  for (; i < n8; i += stride) {
    float4 f0 = ((const float4*)in)[2 * i];
    float4 f1 = ((const float4*)in)[2 * i + 1];
    bf16x8 o;
    o[0] = (__bf16)f0.x; o[1] = (__bf16)f0.y; o[2] = (__bf16)f0.z; o[3] = (__bf16)f0.w;
    o[4] = (__bf16)f1.x; o[5] = (__bf16)f1.y; o[6] = (__bf16)f1.z; o[7] = (__bf16)f1.w;
    ((bf16x8*)out)[i] = o;
  }
}

__global__ void __launch_bounds__(256) cast3_bf16_kernel(
    const float* __restrict__ s0, const float* __restrict__ s1,
    const float* __restrict__ s2, __bf16* __restrict__ dst) {
  int i = blockIdx.x * blockDim.x + threadIdx.x;  // [0, 3*131072)
  int seg = i >> 17, rem = i & 131071;
  const float* s = (seg == 0) ? s0 : ((seg == 1) ? s1 : s2);
  float4 f0 = ((const float4*)s)[2 * rem];
  float4 f1 = ((const float4*)s)[2 * rem + 1];
  bf16x8 o;
  o[0] = (__bf16)f0.x; o[1] = (__bf16)f0.y; o[2] = (__bf16)f0.z; o[3] = (__bf16)f0.w;
  o[4] = (__bf16)f1.x; o[5] = (__bf16)f1.y; o[6] = (__bf16)f1.z; o[7] = (__bf16)f1.w;
  ((bf16x8*)dst)[i] = o;
}

// ---------------------------------------------------------------------------
// QKV GEMM, 8-phase-class schedule with counted vmcnt (T1..T5):
//   C = X @ Wcat^T + b ; fused N=3072 (Wcat = Wq|Wk|Wv contiguous).
//   BM=256, BN=192, BK=64; grid 512 = 32 tm x 16 tn (exactly 2 CU-rounds).
//   8 waves (2M x 4N), wave tile 128x48 (8 mf x 3 nf), 4 phases/K-tile:
//   phase (ks, mf-half) = 12 MFMA. A stored K-half-split [2][256][32cols]
//   so K-half-1 is consumed 2 phases later than K-half-0 -> counted waits.
//   Staging: 7 rounds/tile (1 gload instr/wave each), issue order = consume
//   order (B0,B1,B2,A0r0,A0r1,A1r0,A1r1), spread 2,2,2,1 over phases.
//   Waits: WAITV(2) at ph0, WAITV(4) at ph2 (tail WAITV(0)); no drain.
//   Swizzles (both-sides): A 64B rows chunk^=(row>>1)&3; B 128B rows chunk^=row&7.
// Outputs: z=0 -> Q * (0.125*log2e) ; z=1 -> K ; z=2 -> V^T [B,NH,HD,S]
// ---------------------------------------------------------------------------
#define LDSA(s) (lds + (size_t)(s) * 32768)
#define LDSB(s) (lds + 65536 + (size_t)(s) * 24576)

__global__ void __launch_bounds__(512, 2) qkv_gemm_kernel(
    const __bf16* __restrict__ X, const __bf16* __restrict__ Wcat,
    const float* __restrict__ bq, const float* __restrict__ bk, const float* __restrict__ bv,
    __bf16* __restrict__ Qo, __bf16* __restrict__ Ko, __bf16* __restrict__ Vto) {
  extern __shared__ char lds[];  // 114688 B

  const int tid = threadIdx.x;
  const int lane = tid & 63, w = tid >> 6;
  const int l15 = lane & 15, g = lane >> 4;
  const int wm = w >> 2, wn = w & 3;

  // bijective XCD swizzle: 512 blocks, 64 per XCD
  const int bid = blockIdx.x;
  const int swz = ((bid & 7) << 6) | (bid >> 3);
  const int tm = swz >> 4, tn = swz & 15;
  const int bm0 = tm * 256, n0 = tn * 192;

  const char* Xb = (const char*)X;
  const char* Wb = (const char*)Wcat;

  // ---- staging geometry (pre-swizzled global source, linear LDS dest)
  const int row_b = tid >> 3, scB = ((tid & 7) ^ (row_b & 7));
  const int row_a = tid >> 2, scA = ((tid & 3) ^ ((row_a >> 1) & 3));
  const char* srcB = Wb + (size_t)(n0 + row_b) * 2048 + scB * 16;
  const char* srcA = Xb + (size_t)(bm0 + row_a) * 2048 + scA * 16;

#define STG_B(ss, r, ktb) gload_lds16(srcB + (size_t)(r) * 131072 + (ktb), \
                                      LDSB(ss) + (r) * 8192 + w * 1024)
#define STG_A(ss, h, rb, ktb) gload_lds16(srcA + (size_t)(rb) * 262144 + (h) * 64 + (ktb), \
                                          LDSA(ss) + (h) * 16384 + (rb) * 8192 + w * 1024)

  // ---- ds_read offsets
  const int aoff = (wm * 128 + l15) * 64 + ((g ^ ((l15 >> 1) & 3)) << 4);
  const int boffs = (wn * 48 + l15) * 128;
  const int bsw = l15 & 7;

  f32x4 acc[8][3] = {};

  // ---- prologue: tile 0, consumption order
  STG_B(0, 0, 0); STG_B(0, 1, 0); STG_B(0, 2, 0);
  STG_A(0, 0, 0, 0); STG_A(0, 0, 1, 0);
  STG_A(0, 1, 0, 0); STG_A(0, 1, 1, 0);

#pragma unroll 2
  for (int t = 0; t < 16; ++t) {
    const int s = t & 1, ns = s ^ 1;
    const bool st = t < 15;
    const size_t ktb = (size_t)(t + 1) * 128;
    const char* As = LDSA(s);
    const char* Bs = LDSB(s);

    // ===== ph0: ks=0, mf 0-3  (needs B full + A khalf0)
    WAITV(2);
    SBAR();
    bf16x8 b0 = *(const bf16x8*)(Bs + boffs + 0 * 2048 + ((g ^ bsw) << 4));
    bf16x8 b1 = *(const bf16x8*)(Bs + boffs + 1 * 2048 + ((g ^ bsw) << 4));
    bf16x8 b2 = *(const bf16x8*)(Bs + boffs + 2 * 2048 + ((g ^ bsw) << 4));
    {
      bf16x8 a0 = *(const bf16x8*)(As + aoff + 0 * 1024);
      bf16x8 a1 = *(const bf16x8*)(As + aoff + 1 * 1024);
      bf16x8 a2 = *(const bf16x8*)(As + aoff + 2 * 1024);
      bf16x8 a3 = *(const bf16x8*)(As + aoff + 3 * 1024);
      if (st) { STG_B(ns, 0, ktb); STG_B(ns, 1, ktb); }
      __builtin_amdgcn_s_setprio(1);
      acc[0][0] = __builtin_amdgcn_mfma_f32_16x16x32_bf16(a0, b0, acc[0][0], 0, 0, 0);
      acc[0][1] = __builtin_amdgcn_mfma_f32_16x16x32_bf16(a0, b1, acc[0][1], 0, 0, 0);
      acc[0][2] = __builtin_amdgcn_mfma_f32_16x16x32_bf16(a0, b2, acc[0][2], 0, 0, 0);
      acc[1][0] = __builtin_amdgcn_mfma_f32_16x16x32_bf16(a1, b0, acc[1][0], 0, 0, 0);
      acc[1][1] = __builtin_amdgcn_mfma_f32_16x16x32_bf16(a1, b1, acc[1][1], 0, 0, 0);
      acc[1][2] = __builtin_amdgcn_mfma_f32_16x16x32_bf16(a1, b2, acc[1][2], 0, 0, 0);
      acc[2][0] = __builtin_amdgcn_mfma_f32_16x16x32_bf16(a2, b0, acc[2][0], 0, 0, 0);
      acc[2][1] = __builtin_amdgcn_mfma_f32_16x16x32_bf16(a2, b1, acc[2][1], 0, 0, 0);
      acc[2][2] = __builtin_amdgcn_mfma_f32_16x16x32_bf16(a2, b2, acc[2][2], 0, 0, 0);
      acc[3][0] = __builtin_amdgcn_mfma_f32_16x16x32_bf16(a3, b0, acc[3][0], 0, 0, 0);
      acc[3][1] = __builtin_amdgcn_mfma_f32_16x16x32_bf16(a3, b1, acc[3][1], 0, 0, 0);
      acc[3][2] = __builtin_amdgcn_mfma_f32_16x16x32_bf16(a3, b2, acc[3][2], 0, 0, 0);
      __builtin_amdgcn_s_setprio(0);
    }

    // ===== ph1: ks=0, mf 4-7  (reuse b0..b2)
    SBAR();
    {
      bf16x8 a4 = *(const bf16x8*)(As + aoff + 4 * 1024);
      bf16x8 a5 = *(const bf16x8*)(As + aoff + 5 * 1024);
      bf16x8 a6 = *(const bf16x8*)(As + aoff + 6 * 1024);
      bf16x8 a7 = *(const bf16x8*)(As + aoff + 7 * 1024);
      if (st) { STG_B(ns, 2, ktb); STG_A(ns, 0, 0, ktb); }
      __builtin_amdgcn_s_setprio(1);
      acc[4][0] = __builtin_amdgcn_mfma_f32_16x16x32_bf16(a4, b0, acc[4][0], 0, 0, 0);
      acc[4][1] = __builtin_amdgcn_mfma_f32_16x16x32_bf16(a4, b1, acc[4][1], 0, 0, 0);
      acc[4][2] = __builtin_amdgcn_mfma_f32_16x16x32_bf16(a4, b2, acc[4][2], 0, 0, 0);
      acc[5][0] = __builtin_amdgcn_mfma_f32_16x16x32_bf16(a5, b0, acc[5][0], 0, 0, 0);
      acc[5][1] = __builtin_amdgcn_mfma_f32_16x16x32_bf16(a5, b1, acc[5][1], 0, 0, 0);
      acc[5][2] = __builtin_amdgcn_mfma_f32_16x16x32_bf16(a5, b2, acc[5][2], 0, 0, 0);
      acc[6][0] = __builtin_amdgcn_mfma_f32_16x16x32_bf16(a6, b0, acc[6][0], 0, 0, 0);
      acc[6][1] = __builtin_amdgcn_mfma_f32_16x16x32_bf16(a6, b1, acc[6][1], 0, 0, 0);
      acc[6][2] = __builtin_amdgcn_mfma_f32_16x16x32_bf16(a6, b2, acc[6][2], 0, 0, 0);
      acc[7][0] = __builtin_amdgcn_mfma_f32_16x16x32_bf16(a7, b0, acc[7][0], 0, 0, 0);
      acc[7][1] = __builtin_amdgcn_mfma_f32_16x16x32_bf16(a7, b1, acc[7][1], 0, 0, 0);
      acc[7][2] = __builtin_amdgcn_mfma_f32_16x16x32_bf16(a7, b2, acc[7][2], 0, 0, 0);
      __builtin_amdgcn_s_setprio(0);
    }

    // ===== ph2: ks=1, mf 0-3  (needs A khalf1)
    if (st) { WAITV(4); } else { WAITV(0); }
    SBAR();
    b0 = *(const bf16x8*)(Bs + boffs + 0 * 2048 + (((g + 4) ^ bsw) << 4));
    b1 = *(const bf16x8*)(Bs + boffs + 1 * 2048 + (((g + 4) ^ bsw) << 4));
    b2 = *(const bf16x8*)(Bs + boffs + 2 * 2048 + (((g + 4) ^ bsw) << 4));
    {
      bf16x8 a0 = *(const bf16x8*)(As + 16384 + aoff + 0 * 1024);
      bf16x8 a1 = *(const bf16x8*)(As + 16384 + aoff + 1 * 1024);
      bf16x8 a2 = *(const bf16x8*)(As + 16384 + aoff + 2 * 1024);
      bf16x8 a3 = *(const bf16x8*)(As + 16384 + aoff + 3 * 1024);
      if (st) { STG_A(ns, 0, 1, ktb); STG_A(ns, 1, 0, ktb); }
      __builtin_amdgcn_s_setprio(1);
      acc[0][0] = __builtin_amdgcn_mfma_f32_16x16x32_bf16(a0, b0, acc[0][0], 0, 0, 0);
      acc[0][1] = __builtin_amdgcn_mfma_f32_16x16x32_bf16(a0, b1, acc[0][1], 0, 0, 0);
      acc[0][2] = __builtin_amdgcn_mfma_f32_16x16x32_bf16(a0, b2, acc[0][2], 0, 0, 0);
      acc[1][0] = __builtin_amdgcn_mfma_f32_16x16x32_bf16(a1, b0, acc[1][0], 0, 0, 0);
      acc[1][1] = __builtin_amdgcn_mfma_f32_16x16x32_bf16(a1, b1, acc[1][1], 0, 0, 0);
      acc[1][2] = __builtin_amdgcn_mfma_f32_16x16x32_bf16(a1, b2, acc[1][2], 0, 0, 0);
      acc[2][0] = __builtin_amdgcn_mfma_f32_16x16x32_bf16(a2, b0, acc[2][0], 0, 0, 0);
      acc[2][1] = __builtin_amdgcn_mfma_f32_16x16x32_bf16(a2, b1, acc[2][1], 0, 0, 0);
      acc[2][2] = __builtin_amdgcn_mfma_f32_16x16x32_bf16(a2, b2, acc[2][2], 0, 0, 0);
      acc[3][0] = __builtin_amdgcn_mfma_f32_16x16x32_bf16(a3, b0, acc[3][0], 0, 0, 0);
      acc[3][1] = __builtin_amdgcn_mfma_f32_16x16x32_bf16(a3, b1, acc[3][1], 0, 0, 0);
      acc[3][2] = __builtin_amdgcn_mfma_f32_16x16x32_bf16(a3, b2, acc[3][2], 0, 0, 0);
      __builtin_amdgcn_s_setprio(0);
    }

    // ===== ph3: ks=1, mf 4-7
    SBAR();
    {
      bf16x8 a4 = *(const bf16x8*)(As + 16384 + aoff + 4 * 1024);
      bf16x8 a5 = *(const bf16x8*)(As + 16384 + aoff + 5 * 1024);
      bf16x8 a6 = *(const bf16x8*)(As + 16384 + aoff + 6 * 1024);
      bf16x8 a7 = *(const bf16x8*)(As + 16384 + aoff + 7 * 1024);
      if (st) { STG_A(ns, 1, 1, ktb); }
      __builtin_amdgcn_s_setprio(1);
      acc[4][0] = __builtin_amdgcn_mfma_f32_16x16x32_bf16(a4, b0, acc[4][0], 0, 0, 0);
      acc[4][1] = __builtin_amdgcn_mfma_f32_16x16x32_bf16(a4, b1, acc[4][1], 0, 0, 0);
      acc[4][2] = __builtin_amdgcn_mfma_f32_16x16x32_bf16(a4, b2, acc[4][2], 0, 0, 0);
      acc[5][0] = __builtin_amdgcn_mfma_f32_16x16x32_bf16(a5, b0, acc[5][0], 0, 0, 0);
      acc[5][1] = __builtin_amdgcn_mfma_f32_16x16x32_bf16(a5, b1, acc[5][1], 0, 0, 0);
      acc[5][2] = __builtin_amdgcn_mfma_f32_16x16x32_bf16(a5, b2, acc[5][2], 0, 0, 0);
      acc[6][0] = __builtin_amdgcn_mfma_f32_16x16x32_bf16(a6, b0, acc[6][0], 0, 0, 0);
      acc[6][1] = __builtin_amdgcn_mfma_f32_16x16x32_bf16(a6, b1, acc[6][1], 0, 0, 0);
      acc[6][2] = __builtin_amdgcn_mfma_f32_16x16x32_bf16(a6, b2, acc[6][2], 0, 0, 0);
      acc[7][0] = __builtin_amdgcn_mfma_f32_16x16x32_bf16(a7, b0, acc[7][0], 0, 0, 0);
      acc[7][1] = __builtin_amdgcn_mfma_f32_16x16x32_bf16(a7, b1, acc[7][1], 0, 0, 0);
      acc[7][2] = __builtin_amdgcn_mfma_f32_16x16x32_bf16(a7, b2, acc[7][2], 0, 0, 0);
      __builtin_amdgcn_s_setprio(0);
    }
  }

  // ---- epilogue: C/D frag row=4g+r, col=l15; per-element z select
#pragma unroll
  for (int nf = 0; nf < 3; ++nf) {
    const int ng = n0 + wn * 48 + nf * 16 + l15;  // [0, 3072)
    const int z = ng >> 10;
    const int nzn = ng & 1023;
    const float* bp = (z == 0) ? bq : ((z == 1) ? bk : bv);
    const float bs = bp[nzn];
    const int nh = nzn >> 6, d = nzn & 63;
#pragma unroll
    for (int mf = 0; mf < 8; ++mf) {
#pragma unroll
      for (int r = 0; r < 4; ++r) {
        const int m = bm0 + wm * 128 + mf * 16 + 4 * g + r;
        const int bb = m >> 10, sI = m & 1023;
        const float v = acc[mf][nf][r] + bs;
        if (z == 0) {
          Qo[(((size_t)bb * NH_ + nh) * S_ + sI) * HD_ + d] = (__bf16)(v * (0.125f * LOG2E));
        } else if (z == 1) {
          Ko[(((size_t)bb * NH_ + nh) * S_ + sI) * HD_ + d] = (__bf16)v;
        } else {
          Vto[(((size_t)bb * NH_ + nh) * HD_ + d) * S_ + sI] = (__bf16)v;
        }
      }
    }
  }
}

// ---------------------------------------------------------------------------
// Flash attention, 8-wave 32x32 + K/V double-buffer (unchanged from round 6)
// ---------------------------------------------------------------------------
#define CROW(r, hi) (((r) & 3) + 8 * ((r) >> 2) + 4 * (hi))

__global__ void __launch_bounds__(512) attn_kernel(
    const __bf16* __restrict__ Q,   // [128][1024][64]
    const __bf16* __restrict__ K,   // [128][1024][64]
    const __bf16* __restrict__ Vt,  // [128][64][1024]
    float* __restrict__ Out) {      // [8][1024][1024]
  __shared__ __align__(16) char Ksm[2][8192];
  __shared__ __align__(16) char Vsm[2][8192];
  __shared__ __align__(16) float stat_lds[512];

  const int tid = threadIdx.x, lane = tid & 63, w = tid >> 6;
  const int l31 = lane & 31, hi = lane >> 5;
  const int head = blockIdx.y;
  const int bb = head >> 4, nh = head & 15;
  const int qw = blockIdx.x * 256 + w * 32;

  const char* Qh = (const char*)(Q + (size_t)head * S_ * HD_);
  const char* Kh = (const char*)(K + (size_t)head * S_ * HD_);
  const char* Vh = (const char*)(Vt + (size_t)head * S_ * HD_);

  const int srow = (tid * 16) >> 7;
  const int sinrow = ((tid * 16) & 127) ^ ((srow & 7) << 4);

  bf16x8 qf[4];
#pragma unroll
  for (int slot = 0; slot < 4; ++slot)
    qf[slot] = *reinterpret_cast<const bf16x8*>(
        Qh + (size_t)(qw + l31) * 128 + slot * 32 + hi * 16);

  float m_run = -1e30f, l_run = 0.0f;
  f32x16 accO[2] = {};

  gload_lds16(Kh + (size_t)srow * 128 + sinrow, Ksm[0] + w * 1024);
  gload_lds16(Vh + (size_t)srow * 2048 + sinrow, Vsm[0] + w * 1024);

  for (int t = 0; t < 16; ++t) {
    const int cur = t & 1;
    if (t < 15) {
      const int nxt = cur ^ 1;
      const size_t kvn = (size_t)(t + 1) * 64;
      gload_lds16(Kh + (size_t)(kvn + srow) * 128 + sinrow, Ksm[nxt] + w * 1024);
      gload_lds16(Vh + (size_t)srow * 2048 + kvn * 2 + sinrow, Vsm[nxt] + w * 1024);
      WAITV(2);
    } else {
      WAITV(0);
    }
    SBAR();

    const char* Kc = Ksm[cur];
    const char* Vc = Vsm[cur];

    f32x16 s0 = {}, s1 = {};
    __builtin_amdgcn_s_setprio(1);
#pragma unroll
    for (int slot = 0; slot < 4; ++slot) {
      int c0 = slot * 2 + hi;
      int r0 = l31;
      bf16x8 k0 = *reinterpret_cast<const bf16x8*>(Kc + r0 * 128 + ((c0 ^ (r0 & 7)) << 4));
      int r1 = 32 + l31;
      bf16x8 k1 = *reinterpret_cast<const bf16x8*>(Kc + r1 * 128 + ((c0 ^ (r1 & 7)) << 4));
      s0 = __builtin_amdgcn_mfma_f32_32x32x16_bf16(k0, qf[slot], s0, 0, 0, 0);
      s1 = __builtin_amdgcn_mfma_f32_32x32x16_bf16(k1, qf[slot], s1, 0, 0, 0);
    }
    __builtin_amdgcn_s_setprio(0);

    float mx = -1e30f;
#pragma unroll
    for (int r = 0; r < 16; ++r) mx = fmaxf(mx, fmaxf(s0[r], s1[r]));
    mx = fmaxf(mx, __shfl_xor(mx, 32));
    float mnew = fmaxf(m_run, mx);
    float corr = EXP2(m_run - mnew);
    float sum = 0.0f;
#pragma unroll
    for (int r = 0; r < 16; ++r) {
      float p0 = EXP2(s0[r] - mnew); s0[r] = p0; sum += p0;
      float p1 = EXP2(s1[r] - mnew); s1[r] = p1; sum += p1;
    }
    sum += __shfl_xor(sum, 32);
    l_run = l_run * corr + sum;
    m_run = mnew;

    stat_lds[w * 64 + lane] = corr;
    f32x4 c4[4];
#pragma unroll
    for (int rq = 0; rq < 4; ++rq)
      c4[rq] = *reinterpret_cast<const f32x4*>(&stat_lds[w * 64 + rq * 8 + hi * 4]);
#pragma unroll
    for (int r = 0; r < 16; ++r) {
      float cr = c4[r >> 2][r & 3];
      accO[0][r] *= cr;
      accO[1][r] *= cr;
    }

    bf16x8 pa[4];
#define BUILD_PA(T, rb)                                                     \
    {                                                                       \
      unsigned x1 = pack_bf16(T[rb + 0], T[rb + 1]);                        \
      unsigned x2 = pack_bf16(T[rb + 2], T[rb + 3]);                        \
      unsigned y1 = pack_bf16(T[rb + 4], T[rb + 5]);                        \
      unsigned y2 = pack_bf16(T[rb + 6], T[rb + 7]);                        \
      swapl32(x1, y1);                                                      \
      swapl32(x2, y2);                                                      \
      union { unsigned u[4]; bf16x8 v; } cvt;                               \
      cvt.u[0] = x1; cvt.u[1] = x2; cvt.u[2] = y1; cvt.u[3] = y2;           \
      pa_out = cvt.v;                                                       \
    }
    {
      bf16x8 pa_out;
      BUILD_PA(s0, 0) pa[0] = pa_out;
      BUILD_PA(s0, 8) pa[1] = pa_out;
      BUILD_PA(s1, 0) pa[2] = pa_out;
      BUILD_PA(s1, 8) pa[3] = pa_out;
    }

    __builtin_amdgcn_s_setprio(1);
#pragma unroll
    for (int ks = 0; ks < 4; ++ks) {
#pragma unroll
      for (int dt = 0; dt < 2; ++dt) {
        int rd = dt * 32 + l31;
        int ck = ks * 2 + hi;
        bf16x8 vb = *reinterpret_cast<const bf16x8*>(Vc + rd * 128 + ((ck ^ (rd & 7)) << 4));
        accO[dt] = __builtin_amdgcn_mfma_f32_32x32x16_bf16(pa[ks], vb, accO[dt], 0, 0, 0);
      }
    }
    __builtin_amdgcn_s_setprio(0);

    SBAR();
  }

  stat_lds[w * 64 + lane] = 1.0f / l_run;
  f32x4 li4[4];
#pragma unroll
  for (int rq = 0; rq < 4; ++rq)
    li4[rq] = *reinterpret_cast<const f32x4*>(&stat_lds[w * 64 + rq * 8 + hi * 4]);

  float* Ob = Out + (size_t)bb * S_ * H_ + (size_t)nh * HD_;
#pragma unroll
  for (int r = 0; r < 16; ++r) {
    int qabs = qw + CROW(r, hi);
    float li = li4[r >> 2][r & 3];
#pragma unroll
    for (int dt = 0; dt < 2; ++dt) {
      int d = dt * 32 + l31;
      Ob[(size_t)qabs * H_ + d] = accO[dt][r] * li;
    }
  }
}

// ---------------------------------------------------------------------------
extern "C" void kernel_launch(void* const* d_in, const int* in_sizes, int n_in,
                              void* d_out, int out_size, void* d_ws, size_t ws_size,
                              hipStream_t stream) {
  const float* hs = (const float*)d_in[0];
  const float* Wq = (const float*)d_in[1];
  const float* bq = (const float*)d_in[2];
  const float* Wk = (const float*)d_in[3];
  const float* bk = (const float*)d_in[4];
  const float* Wv = (const float*)d_in[5];
  const float* bv = (const float*)d_in[6];
  float* out = (float*)d_out;
  char* ws = (char*)d_ws;

  size_t off = 0;
  __bf16* Xb  = (__bf16*)(ws + off); off += (size_t)M_ * H_ * 2;
  __bf16* Wqb = (__bf16*)(ws + off); off += (size_t)H_ * H_ * 2;  // Wcat base
  __bf16* Wkb = (__bf16*)(ws + off); off += (size_t)H_ * H_ * 2;
  __bf16* Wvb = (__bf16*)(ws + off); off += (size_t)H_ * H_ * 2;
  __bf16* Qb  = (__bf16*)(ws + off); off += (size_t)M_ * H_ * 2;
  __bf16* Kb  = (__bf16*)(ws + off); off += (size_t)M_ * H_ * 2;
  __bf16* Vtb = (__bf16*)(ws + off); off += (size_t)M_ * H_ * 2;
  (void)Wkb; (void)Wvb;

  // allow 112 KiB dynamic LDS (host-side, capture-safe, deterministic)
  (void)hipFuncSetAttribute((const void*)qkv_gemm_kernel,
                            hipFuncAttributeMaxDynamicSharedMemorySize, 114688);

  cast_bf16_kernel<<<4096, 256, 0, stream>>>(hs, Xb, M_ * H_ / 8);
  cast3_bf16_kernel<<<1536, 256, 0, stream>>>(Wq, Wk, Wv, Wqb);

  qkv_gemm_kernel<<<512, 512, 114688, stream>>>(
      Xb, Wqb, bq, bk, bv, Qb, Kb, Vtb);

  attn_kernel<<<dim3(S_ / 256, B_ * NH_), 512, 0, stream>>>(Qb, Kb, Vtb, out);
}

// Round 8
// 139.143 us; speedup vs baseline: 1.0982x; 1.0982x over previous
//
#include <hip/hip_runtime.h>
#include <hip/hip_bf16.h>
#include <stdint.h>

// Problem constants
#define B_  8
#define S_  1024
#define H_  1024
#define NH_ 16
#define HD_ 64
#define M_  (B_*S_)   // 8192 rows of hidden

using bf16x8 = __attribute__((ext_vector_type(8))) __bf16;
using f32x4  = __attribute__((ext_vector_type(4))) float;
using f32x16 = __attribute__((ext_vector_type(16))) float;
typedef int iv2 __attribute__((ext_vector_type(2)));

#define LOG2E 1.4426950408889634f

#if __has_builtin(__builtin_amdgcn_exp2f)
#define EXP2(x) __builtin_amdgcn_exp2f(x)
#else
#define EXP2(x) exp2f(x)
#endif

#define SBAR() asm volatile("s_barrier" ::: "memory")
#define WAITV(n) asm volatile("s_waitcnt vmcnt(" #n ")" ::: "memory")

// async global->LDS, 16B per lane; lds ptr must be wave-uniform (HW adds lane*16)
__device__ __forceinline__ void gload_lds16(const void* g, void* l) {
  __builtin_amdgcn_global_load_lds(
      (const __attribute__((address_space(1))) unsigned int*)g,
      (__attribute__((address_space(3))) unsigned int*)l, 16, 0, 0);
}

// pack two f32 -> one u32 of 2 bf16 (lo in bits 0-15)
__device__ __forceinline__ unsigned pack_bf16(float lo, float hi) {
  unsigned r;
  asm("v_cvt_pk_bf16_f32 %0, %1, %2" : "=v"(r) : "v"(lo), "v"(hi));
  return r;
}

// swap a.hi32lanes <-> b.lo32lanes
__device__ __forceinline__ void swapl32(unsigned& a, unsigned& b) {
#if __has_builtin(__builtin_amdgcn_permlane32_swap)
  iv2 r = __builtin_amdgcn_permlane32_swap((int)a, (int)b, false, false);
  a = (unsigned)r[0];
  b = (unsigned)r[1];
#else
  unsigned axc = (unsigned)__shfl_xor((int)a, 32);
  unsigned bxc = (unsigned)__shfl_xor((int)b, 32);
  int lane = threadIdx.x & 63;
  unsigned an = (lane < 32) ? a : bxc;
  unsigned bn = (lane < 32) ? axc : b;
  a = an; b = bn;
#endif
}

// ---------------------------------------------------------------------------
// fp32 -> bf16 casts. X: one launch. W's: one fused launch into contiguous dst.
// ---------------------------------------------------------------------------
__global__ void __launch_bounds__(256) cast_bf16_kernel(const float* __restrict__ in,
                                                        __bf16* __restrict__ out, int n8) {
  int i = blockIdx.x * blockDim.x + threadIdx.x;
  int stride = gridDim.x * blockDim.x;
  for (; i < n8; i += stride) {
    float4 f0 = ((const float4*)in)[2 * i];
    float4 f1 = ((const float4*)in)[2 * i + 1];
    bf16x8 o;
    o[0] = (__bf16)f0.x; o[1] = (__bf16)f0.y; o[2] = (__bf16)f0.z; o[3] = (__bf16)f0.w;
    o[4] = (__bf16)f1.x; o[5] = (__bf16)f1.y; o[6] = (__bf16)f1.z; o[7] = (__bf16)f1.w;
    ((bf16x8*)out)[i] = o;
  }
}

__global__ void __launch_bounds__(256) cast3_bf16_kernel(
    const float* __restrict__ s0, const float* __restrict__ s1,
    const float* __restrict__ s2, __bf16* __restrict__ dst) {
  int i = blockIdx.x * blockDim.x + threadIdx.x;  // [0, 3*131072)
  int seg = i >> 17, rem = i & 131071;
  const float* s = (seg == 0) ? s0 : ((seg == 1) ? s1 : s2);
  float4 f0 = ((const float4*)s)[2 * rem];
  float4 f1 = ((const float4*)s)[2 * rem + 1];
  bf16x8 o;
  o[0] = (__bf16)f0.x; o[1] = (__bf16)f0.y; o[2] = (__bf16)f0.z; o[3] = (__bf16)f0.w;
  o[4] = (__bf16)f1.x; o[5] = (__bf16)f1.y; o[6] = (__bf16)f1.z; o[7] = (__bf16)f1.w;
  ((bf16x8*)dst)[i] = o;
}

// ---------------------------------------------------------------------------
// QKV projection GEMM, round-2 structure with BIGGER TILE (new this round):
//   C = X @ W^T + b; BM=256, BN=128, BK=64; 8 waves (4m x 2n), wave 64x64.
//   Grid (32, 8, 3) = 768 blocks = 3 blocks/CU x 256 CU = ONE full round.
//   LDS 48 KB (A 32K + B 16K), single-buffered 2-barrier loop (proven r2).
//   Per-MFMA staged bytes 192 (vs 256 at 128x128) — staging-demand cut 27%.
// Outputs: z=0 -> Q [B,NH,S,HD] * (0.125*log2e) ; z=1 -> K ; z=2 -> V^T
// ---------------------------------------------------------------------------
__global__ void __launch_bounds__(512) qkv_gemm_kernel(
    const __bf16* __restrict__ X,
    const __bf16* __restrict__ Wq, const __bf16* __restrict__ Wk, const __bf16* __restrict__ Wv,
    const float* __restrict__ bq, const float* __restrict__ bk, const float* __restrict__ bv,
    __bf16* __restrict__ Qo, __bf16* __restrict__ Ko, __bf16* __restrict__ Vto) {
  __shared__ __align__(16) char Asm[256 * 128];  // [256 rows][64 k] bf16, swizzled
  __shared__ __align__(16) char Bsm[128 * 128];  // [128 rows][64 k] bf16, swizzled

  const int tid = threadIdx.x;
  const int lane = tid & 63, w = tid >> 6;
  const int l15 = lane & 15, g = lane >> 4;
  const int wm = w >> 1, wn = w & 1;          // 4m x 2n waves
  const int m0 = blockIdx.x * 256;
  const int n0 = blockIdx.y * 128;
  const int z = blockIdx.z;
  const __bf16* W = (z == 0) ? Wq : ((z == 1) ? Wk : Wv);
  const float* bias = (z == 0) ? bq : ((z == 1) ? bk : bv);

  f32x4 acc[4][4] = {};

  for (int kt = 0; kt < H_; kt += 64) {
    __syncthreads();
    // stage A[256][64] (4 rounds) and B[128][64] (2 rounds); pre-swizzled src
#pragma unroll
    for (int is = 0; is < 4; ++is) {
      int q = is * 8192 + tid * 16;            // linear LDS byte this lane fills
      int row = q >> 7;                        // 128B rows
      int inrow = (q & 127) ^ ((row & 7) << 4);
      const char* ga = (const char*)X + (size_t)(m0 + row) * (H_ * 2) + kt * 2 + inrow;
      gload_lds16(ga, Asm + is * 8192 + w * 1024);
    }
#pragma unroll
    for (int is = 0; is < 2; ++is) {
      int q = is * 8192 + tid * 16;
      int row = q >> 7;                        // 0..127
      int inrow = (q & 127) ^ ((row & 7) << 4);
      const char* gb = (const char*)W + (size_t)(n0 + row) * (H_ * 2) + kt * 2 + inrow;
      gload_lds16(gb, Bsm + is * 8192 + w * 1024);
    }
    __syncthreads();
#pragma unroll
    for (int ks = 0; ks < 2; ++ks) {
      bf16x8 a[4], b[4];
#pragma unroll
      for (int i = 0; i < 4; ++i) {
        int row = wm * 64 + i * 16 + l15;
        int chunk = (g + ks * 4) ^ (row & 7);
        a[i] = *reinterpret_cast<const bf16x8*>(Asm + row * 128 + chunk * 16);
      }
#pragma unroll
      for (int j = 0; j < 4; ++j) {
        int row = wn * 64 + j * 16 + l15;
        int chunk = (g + ks * 4) ^ (row & 7);
        b[j] = *reinterpret_cast<const bf16x8*>(Bsm + row * 128 + chunk * 16);
      }
#pragma unroll
      for (int i = 0; i < 4; ++i)
#pragma unroll
        for (int j = 0; j < 4; ++j)
          acc[i][j] = __builtin_amdgcn_mfma_f32_16x16x32_bf16(a[i], b[j], acc[i][j], 0, 0, 0);
    }
  }

  // epilogue: C/D frag row=4g+r, col=l15
#pragma unroll
  for (int i = 0; i < 4; ++i) {
#pragma unroll
    for (int j = 0; j < 4; ++j) {
      int n = n0 + wn * 64 + j * 16 + l15;
      float bs = bias[n];
      int nh = n >> 6, d = n & 63;
#pragma unroll
      for (int r = 0; r < 4; ++r) {
        int m = m0 + wm * 64 + i * 16 + 4 * g + r;
        int bb = m >> 10, s = m & 1023;
        float v = acc[i][j][r] + bs;
        if (z == 0) {
          Qo[(((size_t)bb * NH_ + nh) * S_ + s) * HD_ + d] = (__bf16)(v * (0.125f * LOG2E));
        } else if (z == 1) {
          Ko[(((size_t)bb * NH_ + nh) * S_ + s) * HD_ + d] = (__bf16)v;
        } else {
          Vto[(((size_t)bb * NH_ + nh) * HD_ + d) * S_ + s] = (__bf16)v;
        }
      }
    }
  }
}

// ---------------------------------------------------------------------------
// Flash attention, 8-wave 32x32 + K/V double-buffer (unchanged from round 6)
// ---------------------------------------------------------------------------
#define CROW(r, hi) (((r) & 3) + 8 * ((r) >> 2) + 4 * (hi))

__global__ void __launch_bounds__(512) attn_kernel(
    const __bf16* __restrict__ Q,   // [128][1024][64]
    const __bf16* __restrict__ K,   // [128][1024][64]
    const __bf16* __restrict__ Vt,  // [128][64][1024]
    float* __restrict__ Out) {      // [8][1024][1024]
  __shared__ __align__(16) char Ksm[2][8192];
  __shared__ __align__(16) char Vsm[2][8192];
  __shared__ __align__(16) float stat_lds[512];

  const int tid = threadIdx.x, lane = tid & 63, w = tid >> 6;
  const int l31 = lane & 31, hi = lane >> 5;
  const int head = blockIdx.y;
  const int bb = head >> 4, nh = head & 15;
  const int qw = blockIdx.x * 256 + w * 32;

  const char* Qh = (const char*)(Q + (size_t)head * S_ * HD_);
  const char* Kh = (const char*)(K + (size_t)head * S_ * HD_);
  const char* Vh = (const char*)(Vt + (size_t)head * S_ * HD_);

  const int srow = (tid * 16) >> 7;
  const int sinrow = ((tid * 16) & 127) ^ ((srow & 7) << 4);

  bf16x8 qf[4];
#pragma unroll
  for (int slot = 0; slot < 4; ++slot)
    qf[slot] = *reinterpret_cast<const bf16x8*>(
        Qh + (size_t)(qw + l31) * 128 + slot * 32 + hi * 16);

  float m_run = -1e30f, l_run = 0.0f;
  f32x16 accO[2] = {};

  gload_lds16(Kh + (size_t)srow * 128 + sinrow, Ksm[0] + w * 1024);
  gload_lds16(Vh + (size_t)srow * 2048 + sinrow, Vsm[0] + w * 1024);

  for (int t = 0; t < 16; ++t) {
    const int cur = t & 1;
    if (t < 15) {
      const int nxt = cur ^ 1;
      const size_t kvn = (size_t)(t + 1) * 64;
      gload_lds16(Kh + (size_t)(kvn + srow) * 128 + sinrow, Ksm[nxt] + w * 1024);
      gload_lds16(Vh + (size_t)srow * 2048 + kvn * 2 + sinrow, Vsm[nxt] + w * 1024);
      WAITV(2);
    } else {
      WAITV(0);
    }
    SBAR();

    const char* Kc = Ksm[cur];
    const char* Vc = Vsm[cur];

    f32x16 s0 = {}, s1 = {};
    __builtin_amdgcn_s_setprio(1);
#pragma unroll
    for (int slot = 0; slot < 4; ++slot) {
      int c0 = slot * 2 + hi;
      int r0 = l31;
      bf16x8 k0 = *reinterpret_cast<const bf16x8*>(Kc + r0 * 128 + ((c0 ^ (r0 & 7)) << 4));
      int r1 = 32 + l31;
      bf16x8 k1 = *reinterpret_cast<const bf16x8*>(Kc + r1 * 128 + ((c0 ^ (r1 & 7)) << 4));
      s0 = __builtin_amdgcn_mfma_f32_32x32x16_bf16(k0, qf[slot], s0, 0, 0, 0);
      s1 = __builtin_amdgcn_mfma_f32_32x32x16_bf16(k1, qf[slot], s1, 0, 0, 0);
    }
    __builtin_amdgcn_s_setprio(0);

    float mx = -1e30f;
#pragma unroll
    for (int r = 0; r < 16; ++r) mx = fmaxf(mx, fmaxf(s0[r], s1[r]));
    mx = fmaxf(mx, __shfl_xor(mx, 32));
    float mnew = fmaxf(m_run, mx);
    float corr = EXP2(m_run - mnew);
    float sum = 0.0f;
#pragma unroll
    for (int r = 0; r < 16; ++r) {
      float p0 = EXP2(s0[r] - mnew); s0[r] = p0; sum += p0;
      float p1 = EXP2(s1[r] - mnew); s1[r] = p1; sum += p1;
    }
    sum += __shfl_xor(sum, 32);
    l_run = l_run * corr + sum;
    m_run = mnew;

    stat_lds[w * 64 + lane] = corr;
    f32x4 c4[4];
#pragma unroll
    for (int rq = 0; rq < 4; ++rq)
      c4[rq] = *reinterpret_cast<const f32x4*>(&stat_lds[w * 64 + rq * 8 + hi * 4]);
#pragma unroll
    for (int r = 0; r < 16; ++r) {
      float cr = c4[r >> 2][r & 3];
      accO[0][r] *= cr;
      accO[1][r] *= cr;
    }

    bf16x8 pa[4];
#define BUILD_PA(T, rb)                                                     \
    {                                                                       \
      unsigned x1 = pack_bf16(T[rb + 0], T[rb + 1]);                        \
      unsigned x2 = pack_bf16(T[rb + 2], T[rb + 3]);                        \
      unsigned y1 = pack_bf16(T[rb + 4], T[rb + 5]);                        \
      unsigned y2 = pack_bf16(T[rb + 6], T[rb + 7]);                        \
      swapl32(x1, y1);                                                      \
      swapl32(x2, y2);                                                      \
      union { unsigned u[4]; bf16x8 v; } cvt;                               \
      cvt.u[0] = x1; cvt.u[1] = x2; cvt.u[2] = y1; cvt.u[3] = y2;           \
      pa_out = cvt.v;                                                       \
    }
    {
      bf16x8 pa_out;
      BUILD_PA(s0, 0) pa[0] = pa_out;
      BUILD_PA(s0, 8) pa[1] = pa_out;
      BUILD_PA(s1, 0) pa[2] = pa_out;
      BUILD_PA(s1, 8) pa[3] = pa_out;
    }

    __builtin_amdgcn_s_setprio(1);
#pragma unroll
    for (int ks = 0; ks < 4; ++ks) {
#pragma unroll
      for (int dt = 0; dt < 2; ++dt) {
        int rd = dt * 32 + l31;
        int ck = ks * 2 + hi;
        bf16x8 vb = *reinterpret_cast<const bf16x8*>(Vc + rd * 128 + ((ck ^ (rd & 7)) << 4));
        accO[dt] = __builtin_amdgcn_mfma_f32_32x32x16_bf16(pa[ks], vb, accO[dt], 0, 0, 0);
      }
    }
    __builtin_amdgcn_s_setprio(0);

    SBAR();
  }

  stat_lds[w * 64 + lane] = 1.0f / l_run;
  f32x4 li4[4];
#pragma unroll
  for (int rq = 0; rq < 4; ++rq)
    li4[rq] = *reinterpret_cast<const f32x4*>(&stat_lds[w * 64 + rq * 8 + hi * 4]);

  float* Ob = Out + (size_t)bb * S_ * H_ + (size_t)nh * HD_;
#pragma unroll
  for (int r = 0; r < 16; ++r) {
    int qabs = qw + CROW(r, hi);
    float li = li4[r >> 2][r & 3];
#pragma unroll
    for (int dt = 0; dt < 2; ++dt) {
      int d = dt * 32 + l31;
      Ob[(size_t)qabs * H_ + d] = accO[dt][r] * li;
    }
  }
}

// ---------------------------------------------------------------------------
extern "C" void kernel_launch(void* const* d_in, const int* in_sizes, int n_in,
                              void* d_out, int out_size, void* d_ws, size_t ws_size,
                              hipStream_t stream) {
  const float* hs = (const float*)d_in[0];
  const float* Wq = (const float*)d_in[1];
  const float* bq = (const float*)d_in[2];
  const float* Wk = (const float*)d_in[3];
  const float* bk = (const float*)d_in[4];
  const float* Wv = (const float*)d_in[5];
  const float* bv = (const float*)d_in[6];
  float* out = (float*)d_out;
  char* ws = (char*)d_ws;

  size_t off = 0;
  __bf16* Xb  = (__bf16*)(ws + off); off += (size_t)M_ * H_ * 2;
  __bf16* Wqb = (__bf16*)(ws + off); off += (size_t)H_ * H_ * 2;
  __bf16* Wkb = (__bf16*)(ws + off); off += (size_t)H_ * H_ * 2;
  __bf16* Wvb = (__bf16*)(ws + off); off += (size_t)H_ * H_ * 2;
  __bf16* Qb  = (__bf16*)(ws + off); off += (size_t)M_ * H_ * 2;
  __bf16* Kb  = (__bf16*)(ws + off); off += (size_t)M_ * H_ * 2;
  __bf16* Vtb = (__bf16*)(ws + off); off += (size_t)M_ * H_ * 2;

  cast_bf16_kernel<<<4096, 256, 0, stream>>>(hs, Xb, M_ * H_ / 8);
  cast3_bf16_kernel<<<1536, 256, 0, stream>>>(Wq, Wk, Wv, Wqb);

  qkv_gemm_kernel<<<dim3(M_ / 256, H_ / 128, 3), 512, 0, stream>>>(
      Xb, Wqb, Wkb, Wvb, bq, bk, bv, Qb, Kb, Vtb);

  attn_kernel<<<dim3(S_ / 256, B_ * NH_), 512, 0, stream>>>(Qb, Kb, Vtb, out);
}